// Round 18
// baseline (2015.863 us; speedup 1.0000x reference)
//
#include <hip/hip_runtime.h>
#include <stdint.h>

typedef __attribute__((ext_vector_type(8))) short bf16x8;
typedef __attribute__((ext_vector_type(4))) float f32x4;
typedef __attribute__((ext_vector_type(4))) unsigned int u32x4;

__device__ __forceinline__ unsigned short f2bf(float f) {
  unsigned int u = __float_as_uint(f);
  return (unsigned short)((u + 0x7fffu + ((u >> 16) & 1u)) >> 16);  // RNE
}

__device__ __forceinline__ void gload16(const void* g, void* l) {
  __builtin_amdgcn_global_load_lds((const __attribute__((address_space(1))) void*)g,
                                   (__attribute__((address_space(3))) void*)l, 16, 0, 0);
}

// wave-uniform pointer -> SGPR (HK technique: readfirstlane base hoist)
__device__ __forceinline__ const unsigned short* s_ptr(const unsigned short* p) {
  unsigned lo = __builtin_amdgcn_readfirstlane((unsigned)(uintptr_t)p);
  unsigned hi = __builtin_amdgcn_readfirstlane((unsigned)((uintptr_t)p >> 32));
  return (const unsigned short*)(((uintptr_t)hi << 32) | lo);
}

// ------------------------------------------- halo-only zero (perimeter cells)
__global__ void zero_halo_k(u32x4* __restrict__ p0, u32x4* __restrict__ p1,
                            u32x4* __restrict__ p2, int Hp, int total) {
  int idx = blockIdx.x * 256 + threadIdx.x;
  if (idx >= total) return;
  const int H = Hp - 2;
  const int ncell = 2 * Hp + 2 * H;
  int c = idx & 31;
  int cell = idx >> 5;
  int n = cell / ncell;
  int ci = cell - n * ncell;
  int yp, xp;
  if (ci < Hp)            { yp = 0;               xp = ci; }
  else if (ci < 2 * Hp)   { yp = Hp - 1;          xp = ci - Hp; }
  else if (ci < 2 * Hp + H) { yp = ci - 2 * Hp + 1; xp = 0; }
  else                    { yp = ci - 2 * Hp - H + 1; xp = Hp - 1; }
  const long o = ((long)(n * Hp + yp) * Hp + xp) * 32 + c;
  u32x4 z = {0u, 0u, 0u, 0u};
  p0[o] = z; p1[o] = z; p2[o] = z;
}

// ------------------------------------------- fp32 NHWC -> padded bf16 NHWC
__global__ void conv_in_k(const float* __restrict__ x, unsigned short* __restrict__ dst,
                          int H, int total) {
  int idx = blockIdx.x * 256 + threadIdx.x;
  if (idx >= total) return;
  const int W = H, Hp = H + 2, Wp = H + 2;
  int c8 = idx & 31;
  int rest = idx >> 5;
  int xp = rest % Wp;
  int r2 = rest / Wp;
  int yp = r2 % Hp;
  int n = r2 / Hp;
  u32x4 o = {0u, 0u, 0u, 0u};
  int iy = yp - 1, ix = xp - 1;
  if ((unsigned)iy < (unsigned)H && (unsigned)ix < (unsigned)W) {
    const float* s = x + ((long)((n * H + iy) * W + ix) * 256 + c8 * 8);
    float4 a = *(const float4*)s;
    float4 b = *(const float4*)(s + 4);
    o.x = f2bf(a.x) | ((unsigned)f2bf(a.y) << 16);
    o.y = f2bf(a.z) | ((unsigned)f2bf(a.w) << 16);
    o.z = f2bf(b.x) | ((unsigned)f2bf(b.y) << 16);
    o.w = f2bf(b.z) | ((unsigned)f2bf(b.w) << 16);
  }
  *(u32x4*)(dst + (long)idx * 8) = o;
}

// -------- HWIO fp32 -> bf16 MFMA-fragment layout (verified R2-R17)
__device__ __forceinline__ void w_frag(const float* __restrict__ w,
                                       unsigned short* __restrict__ wTf,
                                       int CoutReal, int NB, int f) {
  int l = f & 63;
  int t2 = f >> 6;
  int ks = t2 & 1;
  int t3 = t2 >> 1;
  int jg = t3 % NB;
  int stage = t3 / NB;
  int col = jg * 16 + (l & 15);
  int kbase = stage * 64 + ks * 32 + ((l >> 4) << 3);
  u32x4 o = {0u, 0u, 0u, 0u};
  if (col < CoutReal) {
    unsigned short v[8];
#pragma unroll
    for (int e = 0; e < 8; ++e)
      v[e] = f2bf(w[(long)(kbase + e) * CoutReal + col]);
    o.x = v[0] | ((unsigned)v[1] << 16);
    o.y = v[2] | ((unsigned)v[3] << 16);
    o.z = v[4] | ((unsigned)v[5] << 16);
    o.w = v[6] | ((unsigned)v[7] << 16);
  }
  *(u32x4*)(wTf + (long)f * 8) = o;
}

// ALL weight prep in one launch: 8 inter layers + cls_out(NB=48) + bbox_out(NB=8)
__global__ void conv_wall_k(const float* __restrict__ cls_w, const float* __restrict__ bbox_w,
                            const float* __restrict__ cls_out_w, const float* __restrict__ bbox_out_w,
                            unsigned short* __restrict__ wT_cls, unsigned short* __restrict__ wT_bbox,
                            unsigned short* __restrict__ wT_cls_out, unsigned short* __restrict__ wT_bbox_out) {
  int idx = blockIdx.x * 256 + threadIdx.x;
  const int N8 = 8 * 73728;                 // 589824
  if (idx < N8) {
    int which = idx / 73728;
    int f = idx - which * 73728;
    int layer = which & 3;
    const float* w = ((which >> 2) ? bbox_w : cls_w) + (long)layer * 589824;
    unsigned short* wTf = ((which >> 2) ? wT_bbox : wT_cls) + (long)layer * 589824;
    w_frag(w, wTf, 256, 16, f);
  } else if (idx < N8 + 221184) {
    w_frag(cls_out_w, wT_cls_out, 720, 48, idx - N8);
  } else if (idx < N8 + 221184 + 36864) {
    w_frag(bbox_out_w, wT_bbox_out, 36, 8, idx - N8 - 221184);
  }
}

// ---------------------------------------------------------------- conv 3x3
// R14 structure + SGPR-hoisted B base (readfirstlane): B-load addressing
// moves from VALU (per-lane 64b adds) to SALU + saddr-form loads.
// 16x16x32 frags, launch_bounds(256,2), B ring-2 from L2, A in-place rotate,
// T14 dbuf staging, T5 setprio, branch fusion via gridDim.z.
template<int NF, bool FINAL>
__global__ __launch_bounds__(256, 2)
void conv3x3_k(const unsigned short* __restrict__ src0,
               const unsigned short* __restrict__ src1,
               const unsigned short* __restrict__ wT0,
               const unsigned short* __restrict__ wT1,
               const float* __restrict__ bias0,
               const float* __restrict__ bias1,
               unsigned short* __restrict__ dstA0,
               unsigned short* __restrict__ dstA1,
               float* __restrict__ dstOut0,
               float* __restrict__ dstOut1,
               int H, int lntx, int lnty,
               int CoutReal0, int CoutReal1, int NB0, int NB1, int ny1)
{
  __shared__ char smem[49152];   // A dbuf: 2 x 24576; epilogue reuses [0,32768)
  const int tid = threadIdx.x;
  const int W = H, Hp = H + 2, RL = H + 2;
  const int np = gridDim.x;
  const int bx = blockIdx.x;
  const int br = blockIdx.z;
  if (br && (int)blockIdx.y >= ny1) return;   // uniform per block: safe
  const unsigned short* src = br ? src1 : src0;
  const unsigned short* wTf = br ? wT1 : wT0;
  const float* bias = br ? bias1 : bias0;
  unsigned short* dstAct = br ? dstA1 : dstA0;
  float* dstOut = br ? dstOut1 : dstOut0;
  const int CoutReal = br ? CoutReal1 : CoutReal0;
  const int NB = br ? NB1 : NB0;

  const int t = (bx & 7) * (np >> 3) + (bx >> 3);      // XCD-chunked swizzle
  const int tx = (t & ((1 << lntx) - 1)) << 4;
  const int ty = ((t >> lntx) & ((1 << lnty) - 1)) << 3;
  const int n_img = t >> (lntx + lnty);
  const int tileN = blockIdx.y * (NF * 32);

  // A staging: 180 halo rows (10y x 18x) x 128 B = 1440 chunks; 6 x 256 thr
  int srcOff[6];
#pragma unroll
  for (int j = 0; j < 6; ++j) {
    int q = j * 256 + tid;
    int hr = q >> 3, c = q & 7;
    if (hr >= 180) hr = 0;                 // tail dup, harmless
    int hy = hr / 18, hx = hr - hy * 18;
    int lch = c ^ (hr & 7);                // inverse swizzle on global source
    srcOff[j] = ((n_img * Hp + ty + hy) * RL + tx + hx) * 256 + lch * 8;
  }

  const int lane = tid & 63;
  const int wv = tid >> 6;
  const int l15 = lane & 15;
  const int k8 = lane >> 4;
  const int pxRow = (wv & 1) * 4;          // wave's first pixel row (of 8)
  const int jgBase = (tileN >> 4) + (wv >> 1) * NF;
  // wave-uniform B base hoisted to SGPR: loads become saddr-form, address
  // arithmetic runs on the scalar pipe.
  const unsigned short* wBs = s_ptr(wTf + (size_t)jgBase * 1024);
  const size_t stageStride = (size_t)NB << 10;
  const int laneOff = lane * 8;

  int rBase[4];
#pragma unroll
  for (int m = 0; m < 4; ++m)
    rBase[m] = (pxRow + m) * 18 + l15;

  f32x4 acc[4][NF];
#pragma unroll
  for (int m = 0; m < 4; ++m)
#pragma unroll
    for (int n = 0; n < NF; ++n)
      acc[m][n] = (f32x4){0.f, 0.f, 0.f, 0.f};

  auto loadB = [&](bf16x8 (&dst)[NF][2], int stage) {
    const unsigned short* bp = wBs + (size_t)stage * stageStride + laneOff;
#pragma unroll
    for (int n = 0; n < NF; ++n)
#pragma unroll
      for (int ks = 0; ks < 2; ++ks)
        dst[n][ks] = *(const bf16x8*)(bp + n * 1024 + ks * 512);
  };
  auto loadAm = [&](bf16x8 (&dst)[2], const char* buf, int tap, int m) {
    const int ky = tap / 3, kx = tap - ky * 3;
    const int rA = rBase[m] + ky * 18 + kx;
    const int a0 = rA * 128 + ((k8 ^ (rA & 7)) << 4);
    dst[0] = *(const bf16x8*)(buf + a0);
    dst[1] = *(const bf16x8*)(buf + (a0 ^ 64));
  };

  bf16x8 avr[4][2];                        // A fragments, in-place rotated
  bf16x8 bb[2][NF][2];                     // B static ring-2
  loadB(bb[0], 0);                         // stage (tap0, cc0)

  // prologue: stage cc=0 into buf0
#pragma unroll
  for (int j = 0; j < 6; ++j)
    gload16(src + srcOff[j], smem + j * 4096 + tid * 16);
  __syncthreads();
#pragma unroll
  for (int m = 0; m < 4; ++m)
    loadAm(avr[m], smem, 0, m);            // av for (cc0, tap0)

#pragma unroll
  for (int cc = 0; cc < 4; ++cc) {
    char* cbuf = smem + (cc & 1) * 24576;
    if (cc < 3) {                          // issue next A slice early (T14)
      char* nbuf = smem + ((cc + 1) & 1) * 24576;
#pragma unroll
      for (int j = 0; j < 6; ++j)
        gload16(src + srcOff[j] + (cc + 1) * 64, nbuf + j * 4096 + tid * 16);
    }
#pragma unroll
    for (int tap = 0; tap < 9; ++tap) {
      const int s = cc * 9 + tap;          // static ring parity for B
      const int cur = s & 1, nxt = cur ^ 1;
      if (cc < 3 || tap < 8)
        loadB(bb[nxt], (tap < 8) ? ((tap + 1) * 4 + cc) : (cc + 1));
      __builtin_amdgcn_s_setprio(1);       // T5
#pragma unroll
      for (int m = 0; m < 4; ++m) {
#pragma unroll
        for (int n = 0; n < NF; ++n) {
          acc[m][n] = __builtin_amdgcn_mfma_f32_16x16x32_bf16(avr[m][0], bb[cur][n][0], acc[m][n], 0, 0, 0);
          acc[m][n] = __builtin_amdgcn_mfma_f32_16x16x32_bf16(avr[m][1], bb[cur][n][1], acc[m][n], 0, 0, 0);
        }
        if (tap < 8)
          loadAm(avr[m], cbuf, tap + 1, m);   // in-place rotate: next tap's frag
      }
      __builtin_amdgcn_s_setprio(0);
    }
    __syncthreads();                       // drains vmcnt: next buf ready; reads done
    if (cc < 3) {                          // av tap0 of next cc (post-barrier)
      const char* nbuf = smem + ((cc + 1) & 1) * 24576;
#pragma unroll
      for (int m = 0; m < 4; ++m)
        loadAm(avr[m], nbuf, 0, m);
    }
  }

  // ---- epilogue. C/D frag: col=l15, px_in_frag=k8*4+r (verified layout).
  if constexpr (FINAL) {
    constexpr int NCOL = NF * 32;
    constexpr int MASK = NCOL / 4 - 1;
    float* cf = (float*)smem;              // [64 px][NCOL co] fp32 per half
#pragma unroll
    for (int h = 0; h < 2; ++h) {
      if (h) __syncthreads();
      if ((wv & 1) == h) {
#pragma unroll
        for (int n = 0; n < NF; ++n) {
          const int col = (wv >> 1) * (NF * 16) + n * 16 + l15;
          const int colG = tileN + col;
          const float bvl = (colG < CoutReal) ? bias[colG] : 0.f;
          const int c32 = col >> 2;
#pragma unroll
          for (int m = 0; m < 4; ++m)
#pragma unroll
            for (int r = 0; r < 4; ++r) {
              const int pxl = m * 16 + (k8 << 2) + r;       // 0..63
              const int phys = (c32 + (k8 & 1) * 4) & MASK; // 2-way max
              cf[pxl * NCOL + phys * 4 + (col & 3)] = acc[m][n][r] + bvl;
            }
        }
      }
      __syncthreads();
#pragma unroll
      for (int it = 0; it < NCOL / 16; ++it) {
        const int q = it * 256 + tid;
        const int pxl = q / (NCOL / 4), c32 = q & MASK;
        const int colG = tileN + c32 * 4;
        if (colG < CoutReal) {
          const int phys = (c32 + ((pxl >> 2) & 1) * 4) & MASK;
          u32x4 v = *(const u32x4*)(cf + pxl * NCOL + phys * 4);
          const int px = h * 64 + pxl;
          const int y = ty + (px >> 4), x = tx + (px & 15);
          const size_t p = ((size_t)(n_img * H + y)) * W + x;
          *(u32x4*)(dstOut + p * CoutReal + colG) = v;
        }
      }
    }
  } else {
    unsigned short* cb = (unsigned short*)smem;   // [128 px][128 co] bf16 = 32 KB
#pragma unroll
    for (int n = 0; n < NF; ++n) {
      const int col = (wv >> 1) * (NF * 16) + n * 16 + l15;
      const float bvl = bias[tileN + col];
      const int c16 = col >> 3;
#pragma unroll
      for (int m = 0; m < 4; ++m)
#pragma unroll
        for (int r = 0; r < 4; ++r) {
          const int px = (wv & 1) * 64 + m * 16 + (k8 << 2) + r;
          const int phys = (c16 + k8 * 2) & 15;             // conflict-free
          cb[px * 128 + phys * 8 + (col & 7)] = f2bf(fmaxf(acc[m][n][r] + bvl, 0.f));
        }
    }
    __syncthreads();
#pragma unroll
    for (int it = 0; it < 8; ++it) {
      const int q = it * 256 + tid;
      const int px = q >> 4, c16 = q & 15;
      const int phys = (c16 + ((px >> 2) & 3) * 2) & 15;
      u32x4 v = *(const u32x4*)(cb + px * 128 + phys * 8);
      const int y = ty + (px >> 4), x = tx + (px & 15);
      const size_t o = ((size_t)(n_img * Hp + y + 1) * RL + x + 1) * 256 + tileN + c16 * 8;
      *(u32x4*)(dstAct + o) = v;
    }
  }
}

// ---------------------------------------------------------------- host
static void run_branch_seq(const unsigned short* In, unsigned short* B1, unsigned short* B2,
                           const unsigned short* wT, const float* bias,
                           const unsigned short* wTout, const float* biasOut,
                           bool cls, float* out, int H, int lntx, int lnty,
                           hipStream_t stream) {
  dim3 blk(256);
  const int np = 8 * (H / 16) * (H / 8);
  dim3 g1(np, 2, 1);
  conv3x3_k<4, false><<<g1, blk, 0, stream>>>(In, In, wT + 0L * 589824, wT, bias, bias, B1, B1, nullptr, nullptr, H, lntx, lnty, 256, 256, 16, 16, 2);
  conv3x3_k<4, false><<<g1, blk, 0, stream>>>(B1, B1, wT + 1L * 589824, wT, bias + 256, bias, B2, B2, nullptr, nullptr, H, lntx, lnty, 256, 256, 16, 16, 2);
  conv3x3_k<4, false><<<g1, blk, 0, stream>>>(B2, B2, wT + 2L * 589824, wT, bias + 512, bias, B1, B1, nullptr, nullptr, H, lntx, lnty, 256, 256, 16, 16, 2);
  conv3x3_k<4, false><<<g1, blk, 0, stream>>>(B1, B1, wT + 3L * 589824, wT, bias + 768, bias, B2, B2, nullptr, nullptr, H, lntx, lnty, 256, 256, 16, 16, 2);
  if (cls) {
    dim3 g2(np, 6, 1);
    conv3x3_k<4, true><<<g2, blk, 0, stream>>>(B2, B2, wTout, wTout, biasOut, biasOut, nullptr, nullptr, out, out, H, lntx, lnty, 720, 720, 48, 48, 6);
  } else {
    dim3 g2(np, 1, 1);
    conv3x3_k<2, true><<<g2, blk, 0, stream>>>(B2, B2, wTout, wTout, biasOut, biasOut, nullptr, nullptr, out, out, H, lntx, lnty, 36, 36, 8, 8, 1);
  }
}

extern "C" void kernel_launch(void* const* d_in, const int* in_sizes, int n_in,
                              void* d_out, int out_size, void* d_ws, size_t ws_size,
                              hipStream_t stream) {
  const float* x[3] = {(const float*)d_in[0], (const float*)d_in[1], (const float*)d_in[2]};
  const float* cls_w      = (const float*)d_in[3];
  const float* cls_b      = (const float*)d_in[4];
  const float* bbox_w     = (const float*)d_in[5];
  const float* bbox_b     = (const float*)d_in[6];
  const float* cls_out_w  = (const float*)d_in[7];
  const float* cls_out_b  = (const float*)d_in[8];
  const float* bbox_out_w = (const float*)d_in[9];
  const float* bbox_out_b = (const float*)d_in[10];
  float* out = (float*)d_out;

  const size_t BUF = 69222400;
  char* ws = (char*)d_ws;
  const bool fused  = ws_size >= 4 * BUF + 15000000;
  const bool triple = !fused && ws_size >= 3 * BUF + 15000000;
  const int nbuf = fused ? 4 : (triple ? 3 : 2);

  unsigned short* I  = (unsigned short*)ws;
  unsigned short* B1 = (unsigned short*)(ws + BUF);
  unsigned short* B2 = (unsigned short*)(ws + 2 * BUF);
  unsigned short* B3 = (unsigned short*)(ws + 3 * BUF);
  unsigned short* wt = (unsigned short*)(ws + (size_t)nbuf * BUF);
  unsigned short* wT_cls      = wt;
  unsigned short* wT_bbox     = wt + 4L * 589824;
  unsigned short* wT_cls_out  = wt + 8L * 589824;          // 1769472 elems
  unsigned short* wT_bbox_out = wT_cls_out + 1769472;      // 294912 elems (NB=8)

  // one launch for ALL weight prep
  conv_wall_k<<<3312, 256, 0, stream>>>(cls_w, bbox_w, cls_out_w, bbox_out_w,
                                        wT_cls, wT_bbox, wT_cls_out, wT_bbox_out);

  const long clsOff[3] = {0L, 94371840L, 117964800L};
  const long boxOff[3] = {123863040L, 128581632L, 129761280L};
  const int Hs[3]    = {128, 64, 32};
  const int lntxs[3] = {3, 2, 1};
  const int lntys[3] = {4, 3, 2};

  for (int lv = 0; lv < 3; ++lv) {
    const int H = Hs[lv], Hp = H + 2;
    const int lntx = lntxs[lv], lnty = lntys[lv];
    const int totalConv = 8 * Hp * Hp * 32;
    const int np = 8 * (H / 16) * (H / 8);
    dim3 blk(256);
    const int haloTotal = 8 * (2 * Hp + 2 * H) * 32;

    if (fused) {
      zero_halo_k<<<(haloTotal + 255) / 256, 256, 0, stream>>>(
          (u32x4*)B1, (u32x4*)B2, (u32x4*)B3, Hp, haloTotal);
      conv_in_k<<<(totalConv + 255) / 256, 256, 0, stream>>>(x[lv], I, H, totalConv);

      dim3 gf(np, 2, 2);
      conv3x3_k<4, false><<<gf, blk, 0, stream>>>(I, I, wT_cls + 0L * 589824, wT_bbox + 0L * 589824,
                                                  cls_b + 0, bbox_b + 0, B1, B2, nullptr, nullptr, H, lntx, lnty, 256, 256, 16, 16, 2);
      conv3x3_k<4, false><<<gf, blk, 0, stream>>>(B1, B2, wT_cls + 1L * 589824, wT_bbox + 1L * 589824,
                                                  cls_b + 256, bbox_b + 256, B3, I, nullptr, nullptr, H, lntx, lnty, 256, 256, 16, 16, 2);
      conv3x3_k<4, false><<<gf, blk, 0, stream>>>(B3, I, wT_cls + 2L * 589824, wT_bbox + 2L * 589824,
                                                  cls_b + 512, bbox_b + 512, B1, B2, nullptr, nullptr, H, lntx, lnty, 256, 256, 16, 16, 2);
      conv3x3_k<4, false><<<gf, blk, 0, stream>>>(B1, B2, wT_cls + 3L * 589824, wT_bbox + 3L * 589824,
                                                  cls_b + 768, bbox_b + 768, B3, I, nullptr, nullptr, H, lntx, lnty, 256, 256, 16, 16, 2);
      // merged finals: z=0 cls (y=0..5, from B3) ; z=1 bbox (y=0 only, from I)
      dim3 gc(np, 6, 2);
      conv3x3_k<4, true><<<gc, blk, 0, stream>>>(B3, I, wT_cls_out, wT_bbox_out,
                                                 cls_out_b, bbox_out_b, nullptr, nullptr,
                                                 out + clsOff[lv], out + boxOff[lv],
                                                 H, lntx, lnty, 720, 36, 48, 8, 1);
    } else {
      unsigned short* pB2 = triple ? B2 : I;
      zero_halo_k<<<(haloTotal + 255) / 256, 256, 0, stream>>>(
          (u32x4*)B1, (u32x4*)(triple ? B2 : B1), (u32x4*)B1, Hp, haloTotal);

      conv_in_k<<<(totalConv + 255) / 256, 256, 0, stream>>>(x[lv], I, H, totalConv);
      run_branch_seq(I, B1, pB2, wT_cls, cls_b, wT_cls_out, cls_out_b,
                     true, out + clsOff[lv], H, lntx, lnty, stream);
      if (!triple)
        conv_in_k<<<(totalConv + 255) / 256, 256, 0, stream>>>(x[lv], I, H, totalConv);
      run_branch_seq(I, B1, pB2, wT_bbox, bbox_b, wT_bbox_out, bbox_out_b,
                     false, out + boxOff[lv], H, lntx, lnty, stream);
    }
  }
}

// Round 19
// 1901.473 us; speedup vs baseline: 1.0602x; 1.0602x over previous
//
#include <hip/hip_runtime.h>
#include <stdint.h>

typedef __attribute__((ext_vector_type(8))) short bf16x8;
typedef __attribute__((ext_vector_type(4))) float f32x4;
typedef __attribute__((ext_vector_type(4))) unsigned int u32x4;

__device__ __forceinline__ unsigned short f2bf(float f) {
  unsigned int u = __float_as_uint(f);
  return (unsigned short)((u + 0x7fffu + ((u >> 16) & 1u)) >> 16);  // RNE
}

__device__ __forceinline__ void gload16(const void* g, void* l) {
  __builtin_amdgcn_global_load_lds((const __attribute__((address_space(1))) void*)g,
                                   (__attribute__((address_space(3))) void*)l, 16, 0, 0);
}

// ------------------------------------------- halo-only zero (perimeter cells)
__global__ void zero_halo_k(u32x4* __restrict__ p0, u32x4* __restrict__ p1,
                            u32x4* __restrict__ p2, int Hp, int total) {
  int idx = blockIdx.x * 256 + threadIdx.x;
  if (idx >= total) return;
  const int H = Hp - 2;
  const int ncell = 2 * Hp + 2 * H;
  int c = idx & 31;
  int cell = idx >> 5;
  int n = cell / ncell;
  int ci = cell - n * ncell;
  int yp, xp;
  if (ci < Hp)            { yp = 0;               xp = ci; }
  else if (ci < 2 * Hp)   { yp = Hp - 1;          xp = ci - Hp; }
  else if (ci < 2 * Hp + H) { yp = ci - 2 * Hp + 1; xp = 0; }
  else                    { yp = ci - 2 * Hp - H + 1; xp = Hp - 1; }
  const long o = ((long)(n * Hp + yp) * Hp + xp) * 32 + c;
  u32x4 z = {0u, 0u, 0u, 0u};
  p0[o] = z; p1[o] = z; p2[o] = z;
}

// ------------------------------------------- fp32 NHWC -> padded bf16 NHWC
__global__ void conv_in_k(const float* __restrict__ x, unsigned short* __restrict__ dst,
                          int H, int total) {
  int idx = blockIdx.x * 256 + threadIdx.x;
  if (idx >= total) return;
  const int W = H, Hp = H + 2, Wp = H + 2;
  int c8 = idx & 31;
  int rest = idx >> 5;
  int xp = rest % Wp;
  int r2 = rest / Wp;
  int yp = r2 % Hp;
  int n = r2 / Hp;
  u32x4 o = {0u, 0u, 0u, 0u};
  int iy = yp - 1, ix = xp - 1;
  if ((unsigned)iy < (unsigned)H && (unsigned)ix < (unsigned)W) {
    const float* s = x + ((long)((n * H + iy) * W + ix) * 256 + c8 * 8);
    float4 a = *(const float4*)s;
    float4 b = *(const float4*)(s + 4);
    o.x = f2bf(a.x) | ((unsigned)f2bf(a.y) << 16);
    o.y = f2bf(a.z) | ((unsigned)f2bf(a.w) << 16);
    o.z = f2bf(b.x) | ((unsigned)f2bf(b.y) << 16);
    o.w = f2bf(b.z) | ((unsigned)f2bf(b.w) << 16);
  }
  *(u32x4*)(dst + (long)idx * 8) = o;
}

// -------- HWIO fp32 -> bf16 MFMA-fragment layout (verified R2-R17)
__device__ __forceinline__ void w_frag(const float* __restrict__ w,
                                       unsigned short* __restrict__ wTf,
                                       int CoutReal, int NB, int f) {
  int l = f & 63;
  int t2 = f >> 6;
  int ks = t2 & 1;
  int t3 = t2 >> 1;
  int jg = t3 % NB;
  int stage = t3 / NB;
  int col = jg * 16 + (l & 15);
  int kbase = stage * 64 + ks * 32 + ((l >> 4) << 3);
  u32x4 o = {0u, 0u, 0u, 0u};
  if (col < CoutReal) {
    unsigned short v[8];
#pragma unroll
    for (int e = 0; e < 8; ++e)
      v[e] = f2bf(w[(long)(kbase + e) * CoutReal + col]);
    o.x = v[0] | ((unsigned)v[1] << 16);
    o.y = v[2] | ((unsigned)v[3] << 16);
    o.z = v[4] | ((unsigned)v[5] << 16);
    o.w = v[6] | ((unsigned)v[7] << 16);
  }
  *(u32x4*)(wTf + (long)f * 8) = o;
}

// ALL weight prep in one launch: 8 inter layers + cls_out(NB=48) + bbox_out(NB=8)
__global__ void conv_wall_k(const float* __restrict__ cls_w, const float* __restrict__ bbox_w,
                            const float* __restrict__ cls_out_w, const float* __restrict__ bbox_out_w,
                            unsigned short* __restrict__ wT_cls, unsigned short* __restrict__ wT_bbox,
                            unsigned short* __restrict__ wT_cls_out, unsigned short* __restrict__ wT_bbox_out) {
  int idx = blockIdx.x * 256 + threadIdx.x;
  const int N8 = 8 * 73728;                 // 589824
  if (idx < N8) {
    int which = idx / 73728;
    int f = idx - which * 73728;
    int layer = which & 3;
    const float* w = ((which >> 2) ? bbox_w : cls_w) + (long)layer * 589824;
    unsigned short* wTf = ((which >> 2) ? wT_bbox : wT_cls) + (long)layer * 589824;
    w_frag(w, wTf, 256, 16, f);
  } else if (idx < N8 + 221184) {
    w_frag(cls_out_w, wT_cls_out, 720, 48, idx - N8);
  } else if (idx < N8 + 221184 + 36864) {
    w_frag(bbox_out_w, wT_bbox_out, 36, 8, idx - N8 - 221184);
  }
}

// ---------------------------------------------------------------- conv 3x3
// FINAL configuration (best measured, R14/R17): 16x16x32 frags,
// launch_bounds(256,2), B ring-2 register stream from L2 (fragment-layout
// weights), A halo staged once per cc-slice via global_load_lds with
// source-side XOR swizzle + T14 issue-early double-buffer, in-place
// m-granular A rotation, T5 setprio around each tap's pure-MFMA cluster,
// branch fusion via gridDim.z. 0 bank conflicts, 0 spill at VGPR 120.
template<int NF, bool FINAL>
__global__ __launch_bounds__(256, 2)
void conv3x3_k(const unsigned short* __restrict__ src0,
               const unsigned short* __restrict__ src1,
               const unsigned short* __restrict__ wT0,
               const unsigned short* __restrict__ wT1,
               const float* __restrict__ bias0,
               const float* __restrict__ bias1,
               unsigned short* __restrict__ dstA0,
               unsigned short* __restrict__ dstA1,
               float* __restrict__ dstOut0,
               float* __restrict__ dstOut1,
               int H, int lntx, int lnty,
               int CoutReal0, int CoutReal1, int NB0, int NB1, int ny1)
{
  __shared__ char smem[49152];   // A dbuf: 2 x 24576; epilogue reuses [0,32768)
  const int tid = threadIdx.x;
  const int W = H, Hp = H + 2, RL = H + 2;
  const int np = gridDim.x;
  const int bx = blockIdx.x;
  const int br = blockIdx.z;
  if (br && (int)blockIdx.y >= ny1) return;   // uniform per block: safe
  const unsigned short* src = br ? src1 : src0;
  const unsigned short* wTf = br ? wT1 : wT0;
  const float* bias = br ? bias1 : bias0;
  unsigned short* dstAct = br ? dstA1 : dstA0;
  float* dstOut = br ? dstOut1 : dstOut0;
  const int CoutReal = br ? CoutReal1 : CoutReal0;
  const int NB = br ? NB1 : NB0;

  const int t = (bx & 7) * (np >> 3) + (bx >> 3);      // XCD-chunked swizzle
  const int tx = (t & ((1 << lntx) - 1)) << 4;
  const int ty = ((t >> lntx) & ((1 << lnty) - 1)) << 3;
  const int n_img = t >> (lntx + lnty);
  const int tileN = blockIdx.y * (NF * 32);

  // A staging: 180 halo rows (10y x 18x) x 128 B = 1440 chunks; 6 x 256 thr
  int srcOff[6];
#pragma unroll
  for (int j = 0; j < 6; ++j) {
    int q = j * 256 + tid;
    int hr = q >> 3, c = q & 7;
    if (hr >= 180) hr = 0;                 // tail dup, harmless
    int hy = hr / 18, hx = hr - hy * 18;
    int lch = c ^ (hr & 7);                // inverse swizzle on global source
    srcOff[j] = ((n_img * Hp + ty + hy) * RL + tx + hx) * 256 + lch * 8;
  }

  const int lane = tid & 63;
  const int wv = tid >> 6;
  const int l15 = lane & 15;
  const int k8 = lane >> 4;
  const int pxRow = (wv & 1) * 4;          // wave's first pixel row (of 8)
  const int jgBase = (tileN >> 4) + (wv >> 1) * NF;
  const unsigned short* wBp = wTf + (size_t)jgBase * 1024 + lane * 8;
  const size_t stageStride = (size_t)NB << 10;

  int rBase[4];
#pragma unroll
  for (int m = 0; m < 4; ++m)
    rBase[m] = (pxRow + m) * 18 + l15;

  f32x4 acc[4][NF];
#pragma unroll
  for (int m = 0; m < 4; ++m)
#pragma unroll
    for (int n = 0; n < NF; ++n)
      acc[m][n] = (f32x4){0.f, 0.f, 0.f, 0.f};

  auto loadB = [&](bf16x8 (&dst)[NF][2], int stage) {
    const unsigned short* bp = wBp + stage * stageStride;
#pragma unroll
    for (int n = 0; n < NF; ++n)
#pragma unroll
      for (int ks = 0; ks < 2; ++ks)
        dst[n][ks] = *(const bf16x8*)(bp + n * 1024 + ks * 512);
  };
  auto loadAm = [&](bf16x8 (&dst)[2], const char* buf, int tap, int m) {
    const int ky = tap / 3, kx = tap - ky * 3;
    const int rA = rBase[m] + ky * 18 + kx;
    const int a0 = rA * 128 + ((k8 ^ (rA & 7)) << 4);
    dst[0] = *(const bf16x8*)(buf + a0);
    dst[1] = *(const bf16x8*)(buf + (a0 ^ 64));
  };

  bf16x8 avr[4][2];                        // A fragments, in-place rotated
  bf16x8 bb[2][NF][2];                     // B static ring-2
  loadB(bb[0], 0);                         // stage (tap0, cc0)

  // prologue: stage cc=0 into buf0
#pragma unroll
  for (int j = 0; j < 6; ++j)
    gload16(src + srcOff[j], smem + j * 4096 + tid * 16);
  __syncthreads();
#pragma unroll
  for (int m = 0; m < 4; ++m)
    loadAm(avr[m], smem, 0, m);            // av for (cc0, tap0)

#pragma unroll
  for (int cc = 0; cc < 4; ++cc) {
    char* cbuf = smem + (cc & 1) * 24576;
    if (cc < 3) {                          // issue next A slice early (T14)
      char* nbuf = smem + ((cc + 1) & 1) * 24576;
#pragma unroll
      for (int j = 0; j < 6; ++j)
        gload16(src + srcOff[j] + (cc + 1) * 64, nbuf + j * 4096 + tid * 16);
    }
#pragma unroll
    for (int tap = 0; tap < 9; ++tap) {
      const int s = cc * 9 + tap;          // static ring parity for B
      const int cur = s & 1, nxt = cur ^ 1;
      if (cc < 3 || tap < 8)
        loadB(bb[nxt], (tap < 8) ? ((tap + 1) * 4 + cc) : (cc + 1));
      __builtin_amdgcn_s_setprio(1);       // T5
#pragma unroll
      for (int m = 0; m < 4; ++m) {
#pragma unroll
        for (int n = 0; n < NF; ++n) {
          acc[m][n] = __builtin_amdgcn_mfma_f32_16x16x32_bf16(avr[m][0], bb[cur][n][0], acc[m][n], 0, 0, 0);
          acc[m][n] = __builtin_amdgcn_mfma_f32_16x16x32_bf16(avr[m][1], bb[cur][n][1], acc[m][n], 0, 0, 0);
        }
        if (tap < 8)
          loadAm(avr[m], cbuf, tap + 1, m);   // in-place rotate: next tap's frag
      }
      __builtin_amdgcn_s_setprio(0);
    }
    __syncthreads();                       // drains vmcnt: next buf ready; reads done
    if (cc < 3) {                          // av tap0 of next cc (post-barrier)
      const char* nbuf = smem + ((cc + 1) & 1) * 24576;
#pragma unroll
      for (int m = 0; m < 4; ++m)
        loadAm(avr[m], nbuf, 0, m);
    }
  }

  // ---- epilogue. C/D frag: col=l15, px_in_frag=k8*4+r (verified layout).
  if constexpr (FINAL) {
    constexpr int NCOL = NF * 32;
    constexpr int MASK = NCOL / 4 - 1;
    float* cf = (float*)smem;              // [64 px][NCOL co] fp32 per half
#pragma unroll
    for (int h = 0; h < 2; ++h) {
      if (h) __syncthreads();
      if ((wv & 1) == h) {
#pragma unroll
        for (int n = 0; n < NF; ++n) {
          const int col = (wv >> 1) * (NF * 16) + n * 16 + l15;
          const int colG = tileN + col;
          const float bvl = (colG < CoutReal) ? bias[colG] : 0.f;
          const int c32 = col >> 2;
#pragma unroll
          for (int m = 0; m < 4; ++m)
#pragma unroll
            for (int r = 0; r < 4; ++r) {
              const int pxl = m * 16 + (k8 << 2) + r;       // 0..63
              const int phys = (c32 + (k8 & 1) * 4) & MASK; // 2-way max
              cf[pxl * NCOL + phys * 4 + (col & 3)] = acc[m][n][r] + bvl;
            }
        }
      }
      __syncthreads();
#pragma unroll
      for (int it = 0; it < NCOL / 16; ++it) {
        const int q = it * 256 + tid;
        const int pxl = q / (NCOL / 4), c32 = q & MASK;
        const int colG = tileN + c32 * 4;
        if (colG < CoutReal) {
          const int phys = (c32 + ((pxl >> 2) & 1) * 4) & MASK;
          u32x4 v = *(const u32x4*)(cf + pxl * NCOL + phys * 4);
          const int px = h * 64 + pxl;
          const int y = ty + (px >> 4), x = tx + (px & 15);
          const size_t p = ((size_t)(n_img * H + y)) * W + x;
          *(u32x4*)(dstOut + p * CoutReal + colG) = v;
        }
      }
    }
  } else {
    unsigned short* cb = (unsigned short*)smem;   // [128 px][128 co] bf16 = 32 KB
#pragma unroll
    for (int n = 0; n < NF; ++n) {
      const int col = (wv >> 1) * (NF * 16) + n * 16 + l15;
      const float bvl = bias[tileN + col];
      const int c16 = col >> 3;
#pragma unroll
      for (int m = 0; m < 4; ++m)
#pragma unroll
        for (int r = 0; r < 4; ++r) {
          const int px = (wv & 1) * 64 + m * 16 + (k8 << 2) + r;
          const int phys = (c16 + k8 * 2) & 15;             // conflict-free
          cb[px * 128 + phys * 8 + (col & 7)] = f2bf(fmaxf(acc[m][n][r] + bvl, 0.f));
        }
    }
    __syncthreads();
#pragma unroll
    for (int it = 0; it < 8; ++it) {
      const int q = it * 256 + tid;
      const int px = q >> 4, c16 = q & 15;
      const int phys = (c16 + ((px >> 2) & 3) * 2) & 15;
      u32x4 v = *(const u32x4*)(cb + px * 128 + phys * 8);
      const int y = ty + (px >> 4), x = tx + (px & 15);
      const size_t o = ((size_t)(n_img * Hp + y + 1) * RL + x + 1) * 256 + tileN + c16 * 8;
      *(u32x4*)(dstAct + o) = v;
    }
  }
}

// ---------------------------------------------------------------- host
static void run_branch_seq(const unsigned short* In, unsigned short* B1, unsigned short* B2,
                           const unsigned short* wT, const float* bias,
                           const unsigned short* wTout, const float* biasOut,
                           bool cls, float* out, int H, int lntx, int lnty,
                           hipStream_t stream) {
  dim3 blk(256);
  const int np = 8 * (H / 16) * (H / 8);
  dim3 g1(np, 2, 1);
  conv3x3_k<4, false><<<g1, blk, 0, stream>>>(In, In, wT + 0L * 589824, wT, bias, bias, B1, B1, nullptr, nullptr, H, lntx, lnty, 256, 256, 16, 16, 2);
  conv3x3_k<4, false><<<g1, blk, 0, stream>>>(B1, B1, wT + 1L * 589824, wT, bias + 256, bias, B2, B2, nullptr, nullptr, H, lntx, lnty, 256, 256, 16, 16, 2);
  conv3x3_k<4, false><<<g1, blk, 0, stream>>>(B2, B2, wT + 2L * 589824, wT, bias + 512, bias, B1, B1, nullptr, nullptr, H, lntx, lnty, 256, 256, 16, 16, 2);
  conv3x3_k<4, false><<<g1, blk, 0, stream>>>(B1, B1, wT + 3L * 589824, wT, bias + 768, bias, B2, B2, nullptr, nullptr, H, lntx, lnty, 256, 256, 16, 16, 2);
  if (cls) {
    dim3 g2(np, 6, 1);
    conv3x3_k<4, true><<<g2, blk, 0, stream>>>(B2, B2, wTout, wTout, biasOut, biasOut, nullptr, nullptr, out, out, H, lntx, lnty, 720, 720, 48, 48, 6);
  } else {
    dim3 g2(np, 1, 1);
    conv3x3_k<2, true><<<g2, blk, 0, stream>>>(B2, B2, wTout, wTout, biasOut, biasOut, nullptr, nullptr, out, out, H, lntx, lnty, 36, 36, 8, 8, 1);
  }
}

extern "C" void kernel_launch(void* const* d_in, const int* in_sizes, int n_in,
                              void* d_out, int out_size, void* d_ws, size_t ws_size,
                              hipStream_t stream) {
  const float* x[3] = {(const float*)d_in[0], (const float*)d_in[1], (const float*)d_in[2]};
  const float* cls_w      = (const float*)d_in[3];
  const float* cls_b      = (const float*)d_in[4];
  const float* bbox_w     = (const float*)d_in[5];
  const float* bbox_b     = (const float*)d_in[6];
  const float* cls_out_w  = (const float*)d_in[7];
  const float* cls_out_b  = (const float*)d_in[8];
  const float* bbox_out_w = (const float*)d_in[9];
  const float* bbox_out_b = (const float*)d_in[10];
  float* out = (float*)d_out;

  const size_t BUF = 69222400;
  char* ws = (char*)d_ws;
  const bool fused  = ws_size >= 4 * BUF + 15000000;
  const bool triple = !fused && ws_size >= 3 * BUF + 15000000;
  const int nbuf = fused ? 4 : (triple ? 3 : 2);

  unsigned short* I  = (unsigned short*)ws;
  unsigned short* B1 = (unsigned short*)(ws + BUF);
  unsigned short* B2 = (unsigned short*)(ws + 2 * BUF);
  unsigned short* B3 = (unsigned short*)(ws + 3 * BUF);
  unsigned short* wt = (unsigned short*)(ws + (size_t)nbuf * BUF);
  unsigned short* wT_cls      = wt;
  unsigned short* wT_bbox     = wt + 4L * 589824;
  unsigned short* wT_cls_out  = wt + 8L * 589824;          // 1769472 elems
  unsigned short* wT_bbox_out = wT_cls_out + 1769472;      // 294912 elems (NB=8)

  // one launch for ALL weight prep
  conv_wall_k<<<3312, 256, 0, stream>>>(cls_w, bbox_w, cls_out_w, bbox_out_w,
                                        wT_cls, wT_bbox, wT_cls_out, wT_bbox_out);

  const long clsOff[3] = {0L, 94371840L, 117964800L};
  const long boxOff[3] = {123863040L, 128581632L, 129761280L};
  const int Hs[3]    = {128, 64, 32};
  const int lntxs[3] = {3, 2, 1};
  const int lntys[3] = {4, 3, 2};

  for (int lv = 0; lv < 3; ++lv) {
    const int H = Hs[lv], Hp = H + 2;
    const int lntx = lntxs[lv], lnty = lntys[lv];
    const int totalConv = 8 * Hp * Hp * 32;
    const int np = 8 * (H / 16) * (H / 8);
    dim3 blk(256);
    const int haloTotal = 8 * (2 * Hp + 2 * H) * 32;

    if (fused) {
      zero_halo_k<<<(haloTotal + 255) / 256, 256, 0, stream>>>(
          (u32x4*)B1, (u32x4*)B2, (u32x4*)B3, Hp, haloTotal);
      conv_in_k<<<(totalConv + 255) / 256, 256, 0, stream>>>(x[lv], I, H, totalConv);

      dim3 gf(np, 2, 2);
      conv3x3_k<4, false><<<gf, blk, 0, stream>>>(I, I, wT_cls + 0L * 589824, wT_bbox + 0L * 589824,
                                                  cls_b + 0, bbox_b + 0, B1, B2, nullptr, nullptr, H, lntx, lnty, 256, 256, 16, 16, 2);
      conv3x3_k<4, false><<<gf, blk, 0, stream>>>(B1, B2, wT_cls + 1L * 589824, wT_bbox + 1L * 589824,
                                                  cls_b + 256, bbox_b + 256, B3, I, nullptr, nullptr, H, lntx, lnty, 256, 256, 16, 16, 2);
      conv3x3_k<4, false><<<gf, blk, 0, stream>>>(B3, I, wT_cls + 2L * 589824, wT_bbox + 2L * 589824,
                                                  cls_b + 512, bbox_b + 512, B1, B2, nullptr, nullptr, H, lntx, lnty, 256, 256, 16, 16, 2);
      conv3x3_k<4, false><<<gf, blk, 0, stream>>>(B1, B2, wT_cls + 3L * 589824, wT_bbox + 3L * 589824,
                                                  cls_b + 768, bbox_b + 768, B3, I, nullptr, nullptr, H, lntx, lnty, 256, 256, 16, 16, 2);
      // merged finals: z=0 cls (y=0..5, from B3) ; z=1 bbox (y=0 only, from I)
      dim3 gc(np, 6, 2);
      conv3x3_k<4, true><<<gc, blk, 0, stream>>>(B3, I, wT_cls_out, wT_bbox_out,
                                                 cls_out_b, bbox_out_b, nullptr, nullptr,
                                                 out + clsOff[lv], out + boxOff[lv],
                                                 H, lntx, lnty, 720, 36, 48, 8, 1);
    } else {
      unsigned short* pB2 = triple ? B2 : I;
      zero_halo_k<<<(haloTotal + 255) / 256, 256, 0, stream>>>(
          (u32x4*)B1, (u32x4*)(triple ? B2 : B1), (u32x4*)B1, Hp, haloTotal);

      conv_in_k<<<(totalConv + 255) / 256, 256, 0, stream>>>(x[lv], I, H, totalConv);
      run_branch_seq(I, B1, pB2, wT_cls, cls_b, wT_cls_out, cls_out_b,
                     true, out + clsOff[lv], H, lntx, lnty, stream);
      if (!triple)
        conv_in_k<<<(totalConv + 255) / 256, 256, 0, stream>>>(x[lv], I, H, totalConv);
      run_branch_seq(I, B1, pB2, wT_bbox, bbox_b, wT_bbox_out, bbox_out_b,
                     false, out + boxOff[lv], H, lntx, lnty, stream);
    }
  }
}